// Round 12
// baseline (237.633 us; speedup 1.0000x reference)
//
#include <hip/hip_runtime.h>
#include <math.h>

#define B_  8
#define S_  4096
#define D_  768     // DIM == D_INNER == 768
#define K_  16      // KK
#define C_  48      // CD
#define N_  16      // NS
#define M_  (B_*S_) // 32768 rows

typedef float  f32x4  __attribute__((ext_vector_type(4)));
typedef __bf16 bf16x8 __attribute__((ext_vector_type(8)));

__device__ __forceinline__ ushort f2bf(float f) {
  uint u = __builtin_bit_cast(uint, f);
  u += 0x7FFFu + ((u >> 16) & 1u);      // round-to-nearest-even
  return (ushort)(u >> 16);
}
__device__ __forceinline__ float bf2f(ushort h) {
  return __builtin_bit_cast(float, (uint)h << 16);
}

// ---------------- f32 -> bf16: x, in_proj rows [0,768), out_proj (one launch, R4-proven)
__global__ __launch_bounds__(256)
void cvt_all(const float* __restrict__ x, const float* __restrict__ w1,
             const float* __restrict__ w2, ushort* __restrict__ xb,
             ushort* __restrict__ wb1, ushort* __restrict__ wb2) {
  const int b = blockIdx.x;
  const float* in; ushort* out; int n4, nb, b0;
  if (b < 2048)      { in = x;  out = xb;  n4 = M_ * D_ / 4; nb = 2048; b0 = 0; }
  else if (b < 2624) { in = w1; out = wb1; n4 = D_ * D_ / 4; nb = 576;  b0 = 2048; }
  else               { in = w2; out = wb2; n4 = D_ * D_ / 4; nb = 576;  b0 = 2624; }
  const int stride = nb * 256;
  for (int i = (b - b0) * 256 + threadIdx.x; i < n4; i += stride) {
    float4 v = *reinterpret_cast<const float4*>(in + (size_t)i * 4);
    ushort4 o;
    o.x = f2bf(v.x); o.y = f2bf(v.y); o.z = f2bf(v.z); o.w = f2bf(v.w);
    *reinterpret_cast<ushort4*>(out + (size_t)i * 4) = o;
  }
}

// ---------------- GEMM1 (m97 structure, bf16 in): u0T = (xb @ W1^T + in_b), TRANSPOSED [c][l] bf16
__global__ __launch_bounds__(256)
void gemm1_bt(const ushort* __restrict__ A, const ushort* __restrict__ Bm,
              const float* __restrict__ in_b, ushort* __restrict__ u0T)
{
  __shared__ ushort As[128 * 32];
  __shared__ ushort Bs[128 * 32];

  const int lin = blockIdx.x;
  const int swz = (lin & 7) * 192 + (lin >> 3);   // XCD swizzle (1536%8==0 bijective)
  const int bn  = (swz % 6) * 128;
  const int bm  = (swz / 6) * 128;

  const int tid  = threadIdx.x;
  const int wid  = tid >> 6, lane = tid & 63;
  const int wr   = wid >> 1, wc   = wid & 1;
  const int lr   = lane & 15, lg  = lane >> 4;
  const int srow = lane >> 2;
  const int scol = (lane & 3) * 8;

  f32x4 acc[4][4];
#pragma unroll
  for (int i = 0; i < 4; ++i)
#pragma unroll
    for (int j = 0; j < 4; ++j) acc[i][j] = (f32x4){0.f, 0.f, 0.f, 0.f};

  for (int k0 = 0; k0 < 768; k0 += 32) {
#pragma unroll
    for (int jj = 0; jj < 2; ++jj) {
      const int j = wid * 2 + jj;
      const ushort* ga = A  + (size_t)(bm + j * 16 + srow) * 768 + k0 + scol;
      __builtin_amdgcn_global_load_lds(
          (const __attribute__((address_space(1))) void*)ga,
          (__attribute__((address_space(3))) void*)(As + j * 512), 16, 0, 0);
      const ushort* gb = Bm + (size_t)(bn + j * 16 + srow) * 768 + k0 + scol;
      __builtin_amdgcn_global_load_lds(
          (const __attribute__((address_space(1))) void*)gb,
          (__attribute__((address_space(3))) void*)(Bs + j * 512), 16, 0, 0);
    }
    __syncthreads();

    bf16x8 af[4], bfr[4];
    const int ab = (wr * 64 + lr) * 32 + lg * 8;
    const int bb = (wc * 64 + lr) * 32 + lg * 8;
#pragma unroll
    for (int mf = 0; mf < 4; ++mf) af[mf]  = *reinterpret_cast<const bf16x8*>(&As[ab + mf * 512]);
#pragma unroll
    for (int nf = 0; nf < 4; ++nf) bfr[nf] = *reinterpret_cast<const bf16x8*>(&Bs[bb + nf * 512]);
#pragma unroll
    for (int mf = 0; mf < 4; ++mf)
#pragma unroll
      for (int nf = 0; nf < 4; ++nf)
        acc[mf][nf] = __builtin_amdgcn_mfma_f32_16x16x32_bf16(af[mf], bfr[nf], acc[mf][nf], 0, 0, 0);
    __syncthreads();
  }

  // epilogue (R9-proven): transposed store u0T[(b*768 + c)*4096 + l], 8B per lane
  const int b   = bm >> 12;
  const int l0g = (bm & 4095) + wr * 64;
#pragma unroll
  for (int nf = 0; nf < 4; ++nf) {
    const int cg = bn + wc * 64 + nf * 16 + lr;
    const float bv = in_b[cg];
    ushort* up = u0T + ((size_t)b * 768 + cg) * 4096 + l0g;
#pragma unroll
    for (int mf = 0; mf < 4; ++mf) {
      ushort4 o;
      o.x = f2bf(acc[mf][nf][0] + bv);
      o.y = f2bf(acc[mf][nf][1] + bv);
      o.z = f2bf(acc[mf][nf][2] + bv);
      o.w = f2bf(acc[mf][nf][3] + bv);
      *reinterpret_cast<ushort4*>(up + mf * 16 + lg * 4) = o;
    }
  }
}

// ---------------- fused middle (R9/R11, passing): conv3+silu via unconditional shfl +
// halo select, softplus(delta), einsum, d*d*u*s, [l][c] store.
#define YSP 70

__global__ __launch_bounds__(256)
void fuse_mid(const ushort* __restrict__ u0T, const float* __restrict__ delta,
              const float* __restrict__ Bt, const float* __restrict__ Ct,
              const float* __restrict__ Alog, const float* __restrict__ convw,
              const float* __restrict__ convb, const float* __restrict__ dbias,
              ushort* __restrict__ yT)
{
  __shared__ float  Gs [N_ * 64];       // [n][dl]  B*C products (4 KB)
  __shared__ float  Ak [C_ * N_];       // [c][n]   A rows (3 KB, broadcast reads)
  __shared__ ushort Ys [C_ * YSP];      // [c][dl]  result bounce (6.6 KB)
  __shared__ float  Wk0[C_], Wk1[C_], Wk2[C_], CB[C_], DB[C_];

  const int tid = threadIdx.x;
  const int wid = tid >> 6, lane = tid & 63;
  const int lt = blockIdx.x, k = blockIdx.y, b = blockIdx.z;
  const int l0 = lt * 64;

  for (int idx = tid; idx < N_ * 64; idx += 256) {
    const int n = idx >> 6, dl = idx & 63;
    const size_t gg = (((size_t)b * K_ + k) * N_ + n) * S_ + l0 + dl;
    Gs[idx] = Bt[gg] * Ct[gg];
  }
  for (int idx = tid; idx < C_ * N_; idx += 256)
    Ak[idx] = Alog[(size_t)k * C_ * N_ + idx];
  if (tid < C_) {
    Wk0[tid] = convw[(k * C_ + tid) * 9 + 1];   // only kw=1 column in-bounds (W=1, pad 1)
    Wk1[tid] = convw[(k * C_ + tid) * 9 + 4];
    Wk2[tid] = convw[(k * C_ + tid) * 9 + 7];
    CB [tid] = convb[k * C_ + tid];
    DB [tid] = dbias[k * C_ + tid];
  }
  __syncthreads();

  float g[N_];
#pragma unroll
  for (int n = 0; n < N_; ++n) g[n] = Gs[n * 64 + lane];

  const int  gl = l0 + lane;
  const size_t base = ((size_t)b * D_ + k * C_ + wid) * S_ + gl;
  const float*  dp = delta + base;
  const ushort* up = u0T + base;
  const size_t cs = (size_t)4 * S_;

  const bool edge_lo = (lane == 0);
  const bool edge_hi = (lane == 63);
  const int  hoff    = edge_lo ? -1 : 1;
  const bool h_ok    = (edge_lo && gl > 0) || (edge_hi && gl + 1 < S_);

  float dA = dp[0];
  float uA = bf2f(up[0]);
  float hA = h_ok ? bf2f(up[hoff]) : 0.f;
  float dB = dp[cs];
  float uB = bf2f(up[cs]);
  float hB = h_ok ? bf2f(up[cs + hoff]) : 0.f;

  for (int step = 0; step < 12; ++step) {
    const int c = step * 4 + wid;
    const float dcur = dA, u0v = uA, hv = hA;
    dA = dB; uA = uB; hA = hB;
    if (step < 10) {
      const size_t off = (size_t)(step + 2) * cs;
      dB = dp[off];
      uB = bf2f(up[off]);
      hB = h_ok ? bf2f(up[off + hoff]) : 0.f;
    }

    float a[N_];
#pragma unroll
    for (int n4i = 0; n4i < 4; ++n4i)   // broadcast ds_read_b128 x4 (uniform address)
      *reinterpret_cast<f32x4*>(&a[n4i * 4]) =
          *reinterpret_cast<const f32x4*>(&Ak[c * N_ + n4i * 4]);

    // conv neighbors: shuffles executed UNCONDITIONALLY by all 64 lanes, then select halo
    const float sm = __shfl(u0v, (lane + 63) & 63, 64);
    const float sp = __shfl(u0v, (lane + 1)  & 63, 64);
    const float um  = edge_lo ? hv : sm;
    const float upv = edge_hi ? hv : sp;

    const float dv = dcur + DB[c];
    const float d  = (dv > 15.f) ? dv : __logf(1.f + __expf(dv));   // softplus

    float xx = fmaf(Wk0[c], um, fmaf(Wk1[c], u0v, fmaf(Wk2[c], upv, CB[c])));
    const float u = xx * __builtin_amdgcn_rcpf(1.f + __expf(-xx));  // silu

    float s = 0.f;
#pragma unroll
    for (int n = 0; n < N_; ++n) s = fmaf(a[n], g[n], s);

    Ys[c * YSP + lane] = f2bf(d * d * u * s);
  }
  __syncthreads();

  // [l][c] store as packed uints (2 channels per store); incremental div (256 = 10*24+16)
  {
    uint* yTu = reinterpret_cast<uint*>(yT);
    int dl = tid / 24, j = tid - (tid / 24) * 24;
    for (int e = tid; e < 64 * 24; e += 256) {
      const uint lo = Ys[(2 * j    ) * YSP + dl];
      const uint hi = Ys[(2 * j + 1) * YSP + dl];
      yTu[((size_t)b * S_ + l0 + dl) * 384 + k * 24 + j] = lo | (hi << 16);
      dl += 10; j += 16; if (j >= 24) { j -= 24; dl += 1; }
    }
  }
}

// ---------------- GEMM2 (m97 structure, proven ~58 µs): out = yT @ W2^T + out_b (f32 out)
__global__ __launch_bounds__(256)
void gemm_mfma_bt(const ushort* __restrict__ A, const ushort* __restrict__ Bm,
                  const float* __restrict__ bias, float* __restrict__ Cc)
{
  __shared__ ushort As[128 * 32];
  __shared__ ushort Bs[128 * 32];

  const int lin = blockIdx.x;
  const int swz = (lin & 7) * 192 + (lin >> 3);
  const int bn  = (swz % 6) * 128;
  const int bm  = (swz / 6) * 128;

  const int tid  = threadIdx.x;
  const int wid  = tid >> 6, lane = tid & 63;
  const int wr   = wid >> 1, wc   = wid & 1;
  const int lr   = lane & 15, lg  = lane >> 4;
  const int srow = lane >> 2;
  const int scol = (lane & 3) * 8;

  f32x4 acc[4][4];
#pragma unroll
  for (int i = 0; i < 4; ++i)
#pragma unroll
    for (int j = 0; j < 4; ++j) acc[i][j] = (f32x4){0.f, 0.f, 0.f, 0.f};

  for (int k0 = 0; k0 < 768; k0 += 32) {
#pragma unroll
    for (int jj = 0; jj < 2; ++jj) {
      const int j = wid * 2 + jj;
      const ushort* ga = A  + (size_t)(bm + j * 16 + srow) * 768 + k0 + scol;
      __builtin_amdgcn_global_load_lds(
          (const __attribute__((address_space(1))) void*)ga,
          (__attribute__((address_space(3))) void*)(As + j * 512), 16, 0, 0);
      const ushort* gb = Bm + (size_t)(bn + j * 16 + srow) * 768 + k0 + scol;
      __builtin_amdgcn_global_load_lds(
          (const __attribute__((address_space(1))) void*)gb,
          (__attribute__((address_space(3))) void*)(Bs + j * 512), 16, 0, 0);
    }
    __syncthreads();

    bf16x8 af[4], bfr[4];
    const int ab = (wr * 64 + lr) * 32 + lg * 8;
    const int bb = (wc * 64 + lr) * 32 + lg * 8;
#pragma unroll
    for (int mf = 0; mf < 4; ++mf) af[mf]  = *reinterpret_cast<const bf16x8*>(&As[ab + mf * 512]);
#pragma unroll
    for (int nf = 0; nf < 4; ++nf) bfr[nf] = *reinterpret_cast<const bf16x8*>(&Bs[bb + nf * 512]);
#pragma unroll
    for (int mf = 0; mf < 4; ++mf)
#pragma unroll
      for (int nf = 0; nf < 4; ++nf)
        acc[mf][nf] = __builtin_amdgcn_mfma_f32_16x16x32_bf16(af[mf], bfr[nf], acc[mf][nf], 0, 0, 0);
    __syncthreads();
  }

#pragma unroll
  for (int nf = 0; nf < 4; ++nf) {
    const int n  = bn + wc * 64 + nf * 16 + lr;
    const float bv = bias[n];
#pragma unroll
    for (int mf = 0; mf < 4; ++mf) {
      const int m0 = bm + wr * 64 + mf * 16 + lg * 4;
#pragma unroll
      for (int r = 0; r < 4; ++r)
        Cc[(size_t)(m0 + r) * 768 + n] = acc[mf][nf][r] + bv;
    }
  }
}

extern "C" void kernel_launch(void* const* d_in, const int* in_sizes, int n_in,
                              void* d_out, int out_size, void* d_ws, size_t ws_size,
                              hipStream_t stream) {
  const float* x      = (const float*)d_in[0];
  const float* in_w   = (const float*)d_in[1];   // (1536,768) — only rows [0,768) used
  const float* in_b   = (const float*)d_in[2];
  const float* convw  = (const float*)d_in[3];
  const float* convb  = (const float*)d_in[4];
  const float* out_w  = (const float*)d_in[5];
  const float* out_b  = (const float*)d_in[6];
  const float* Alog   = (const float*)d_in[7];
  const float* delta  = (const float*)d_in[8];
  const float* Bt     = (const float*)d_in[9];
  const float* Ct     = (const float*)d_in[10];
  const float* dbias  = (const float*)d_in[11];
  float* out = (float*)d_out;

  ushort* xb  = (ushort*)d_ws;               // (B,S,768) bf16
  ushort* u0T = xb  + (size_t)M_ * D_;       // (B,768,S) bf16 — TRANSPOSED u0
  ushort* yTb = u0T + (size_t)M_ * D_;       // (B,S,768) bf16
  ushort* wb1 = yTb + (size_t)M_ * D_;
  ushort* wb2 = wb1 + (size_t)D_ * D_;

  cvt_all<<<3200, 256, 0, stream>>>(x, in_w, out_w, xb, wb1, wb2);
  gemm1_bt<<<1536, 256, 0, stream>>>(xb, wb1, in_b, u0T);
  fuse_mid<<<dim3(S_ / 64, K_, B_), 256, 0, stream>>>(u0T, delta, Bt, Ct, Alog,
                                                      convw, convb, dbias, yTb);
  gemm_mfma_bt<<<1536, 256, 0, stream>>>(yTb, wb2, out_b, out);
}